// Round 3
// baseline (61675.641 us; speedup 1.0000x reference)
//
#include <hip/hip_runtime.h>
#include <stdint.h>

// DecoderRNN: 2-layer GRU, H=512, B=64, T=1024, OUT=1, autoregressive scalar feedback.
// Persistent kernel: 256 WGs x 512 threads, 1 WG/CU, 3 single-level device barriers/step.
// R2: single-level epoch barrier (all WGs poll all slots; no master round-trip),
//     register prefetch of h1c (during P1) and next-step h0c (during P2a) to hide
//     the two prefetchable 64KB stagings behind compute + barrier wait.

#define HH   512
#define TT   1024
#define NWG  256
#define NT   512
#define HPAD 516   // hbuf row stride (floats); 16B-aligned, breaks bank conflicts

struct __align__(16) Smem {
  float Wh0[12*HH];    // W_hh0 rows {g*512 + n0+nl}, layout [(g*4+nl)*512 + k]
  float Wi1[12*HH];
  float Wh1[12*HH];
  float Wo1[4*HH];
  float hbuf[32*HPAD]; // staged activation rows [bb][k], padded
  float gictx[12*32];
  float gi1s[12*32];
  float wcol[12];
  float bhh0[12];
  float bih1[12];
  float bhh1[12];
  float bo1v[4];
  float wo2v[4];
  float prevS[32];
  float outred[32];
  float bo2S;
};

__device__ __forceinline__ float sigm(float x){ return 1.f/(1.f + expf(-x)); }

// Single-level epoch barrier: every WG's wave0 polls all NWG slots.
// slots live in d_ws (0xAA poison is negative as int -> can't satisfy >= e).
// Release on arrival publishes this WG's global writes; acquire fence after
// all slots observed imports other WGs' writes (L1/L2 inv).
__device__ __forceinline__ void gbar(int* slots, int w, int tid, int e){
  __syncthreads();
  if (tid == 0)
    __hip_atomic_store(&slots[w], e, __ATOMIC_RELEASE, __HIP_MEMORY_SCOPE_AGENT);
  if (tid < 64){
    for(;;){
      int m0 = __hip_atomic_load(&slots[tid*4+0], __ATOMIC_RELAXED, __HIP_MEMORY_SCOPE_AGENT);
      int m1 = __hip_atomic_load(&slots[tid*4+1], __ATOMIC_RELAXED, __HIP_MEMORY_SCOPE_AGENT);
      int m2 = __hip_atomic_load(&slots[tid*4+2], __ATOMIC_RELAXED, __HIP_MEMORY_SCOPE_AGENT);
      int m3 = __hip_atomic_load(&slots[tid*4+3], __ATOMIC_RELAXED, __HIP_MEMORY_SCOPE_AGENT);
      int mn = min(min(m0,m1), min(m2,m3));
      if (__all(mn >= e)) break;
      __builtin_amdgcn_s_sleep(1);
    }
    if (tid == 0)
      __builtin_amdgcn_fence(__ATOMIC_ACQUIRE, "agent");
  }
  __syncthreads();
}

extern "C" __global__ void __launch_bounds__(NT, 1)
decoder_rnn(const float* __restrict__ ctx,   // [64][512]
            const float* __restrict__ Wih0,  // [1536][513]  (row stride 513)
            const float* __restrict__ Whh0,  // [1536][512]
            const float* __restrict__ bih0,
            const float* __restrict__ bhh0g,
            const float* __restrict__ Wih1,
            const float* __restrict__ Whh1,
            const float* __restrict__ bih1g,
            const float* __restrict__ bhh1g,
            const float* __restrict__ Wo1,
            const float* __restrict__ bo1g,
            const float* __restrict__ Wo2,
            const float* __restrict__ bo2g,
            float* __restrict__ out,         // [65536 outputs][65536 h_i]
            float* __restrict__ ws)
{
  extern __shared__ char smem_raw[];
  Smem& S = *reinterpret_cast<Smem*>(smem_raw);
  const int tid = threadIdx.x;
  const int w   = blockIdx.x;
  const int bg  = w >> 7, ng = w & 127;
  const int b0  = bg * 32, n0 = ng * 4;

  float* h0A   = ws;
  float* h0B   = ws + 32768;
  float* h1A   = ws + 65536;
  float* h1B   = ws + 98304;
  float* outac = ws + 131072;            // [1024][64] raw (pre-relu, pre-bias) sums
  int*   slots = (int*)(ws + 196608);

  // ---------------- init (all before first barrier) ----------------
  if (tid < 128){ h0A[w*128 + tid] = 0.f; h1A[w*128 + tid] = 0.f; }
  if (tid < 256) outac[w*256 + tid] = 0.f;

  for (int i = tid; i < 12*HH; i += NT){
    int rl = i >> 9, k = i & 511;
    int g = rl >> 2, nli = rl & 3;
    int grow = g*HH + n0 + nli;
    S.Wh0[i] = Whh0[(size_t)grow*HH + k];
    S.Wi1[i] = Wih1[(size_t)grow*HH + k];
    S.Wh1[i] = Whh1[(size_t)grow*HH + k];
  }
  for (int i = tid; i < 4*HH; i += NT){
    int nli = i >> 9, k = i & 511;
    S.Wo1[i] = Wo1[(size_t)(n0+nli)*HH + k];
  }
  if (tid < 12){
    int g = tid >> 2, nli = tid & 3;
    int grow = g*HH + n0 + nli;
    S.wcol[tid] = Wih0[(size_t)grow*513 + 512];
    S.bhh0[tid] = bhh0g[grow];
    S.bih1[tid] = bih1g[grow];
    S.bhh1[tid] = bhh1g[grow];
  }
  if (tid < 4){ S.bo1v[tid] = bo1g[n0+tid]; S.wo2v[tid] = Wo2[n0+tid]; }
  if (tid == 0) S.bo2S = bo2g[0];

  // gi_ctx = ctx @ W_ih0[:, :512].T + b_ih0 for our 12 rows x 32 batch (one-time)
  if (tid < 384){
    int rl = tid >> 5, bb = tid & 31;
    int g = rl >> 2, nli = rl & 3;
    int grow = g*HH + n0 + nli;
    const float* wr = Wih0 + (size_t)grow * 513;
    const float* cx = ctx  + (size_t)(b0+bb) * HH;
    float s = bih0[grow];
    for (int k = 0; k < HH; k += 4)
      s += wr[k]*cx[k] + wr[k+1]*cx[k+1] + wr[k+2]*cx[k+2] + wr[k+3]*cx[k+3];
    S.gictx[rl*32 + bb] = s;
  }

  gbar(slots, w, tid, 1);

  // per-thread dot mapping: 128 items (nl in [0,4), bb in [0,32)) x 4 K-parts
  const int p  = tid & 3;
  const int it = tid >> 2;
  const int bb = it & 31;
  const int nl = it >> 5;
  float4* hb4 = (float4*)(S.hbuf) + bb * (HPAD/4);

  // stage 32 rows x 512 floats from global into S.hbuf (padded)
  auto stage = [&](const float* src){
    const float4* s4 = (const float4*)(src + (size_t)b0 * HH);
    #pragma unroll
    for (int i = tid; i < 4096; i += NT){
      int r = i >> 7, c = i & 127;
      *((float4*)(S.hbuf + r*HPAD) + c) = s4[r*128 + c];
    }
  };

  // register prefetch: same item mapping as stage()
  const int pr_r = tid >> 7;         // 0..3 within each 512-item slab
  const int pr_c = tid & 127;
  auto pfload = [&](const float* src, float4* pf){
    const float4* s4 = (const float4*)(src + (size_t)b0 * HH);
    #pragma unroll
    for (int s = 0; s < 8; ++s)
      pf[s] = s4[(s*4 + pr_r)*128 + pr_c];
  };
  auto pfstore = [&](const float4* pf){
    #pragma unroll
    for (int s = 0; s < 8; ++s)
      *((float4*)(S.hbuf + (s*4 + pr_r)*HPAD) + pr_c) = pf[s];
  };

  // 3 gate-row dots of length 512 vs S.hbuf row bb; K split 4-way across p
  auto dot3 = [&](const float* Wbase, float& a0, float& a1, float& a2){
    const float4* w40 = (const float4*)Wbase + nl*128;
    const float4* w41 = w40 + 512;
    const float4* w42 = w41 + 512;
    float s0 = 0.f, s1 = 0.f, s2 = 0.f;
    #pragma unroll 8
    for (int m = 0; m < 32; ++m){
      int idx = p + 4*m;
      float4 h4 = hb4[idx];
      float4 q0 = w40[idx], q1 = w41[idx], q2 = w42[idx];
      s0 += h4.x*q0.x + h4.y*q0.y + h4.z*q0.z + h4.w*q0.w;
      s1 += h4.x*q1.x + h4.y*q1.y + h4.z*q1.z + h4.w*q1.w;
      s2 += h4.x*q2.x + h4.y*q2.y + h4.z*q2.z + h4.w*q2.w;
    }
    s0 += __shfl_xor(s0,1); s0 += __shfl_xor(s0,2);
    s1 += __shfl_xor(s1,1); s1 += __shfl_xor(s1,2);
    s2 += __shfl_xor(s2,1); s2 += __shfl_xor(s2,2);
    a0 = s0; a1 = s1; a2 = s2;
  };

  float4 pfH1[8];   // h1c prefetch (issued P1, consumed P2b)
  float4 pfH0[8];   // next-step h0c prefetch (issued P2a, consumed next P1)

  for (int t = 0; t < TT; ++t){
    const float* h0c = (t & 1) ? h0B : h0A;
    float*       h0n = (t & 1) ? h0A : h0B;
    const float* h1c = (t & 1) ? h1B : h1A;
    float*       h1n = (t & 1) ? h1A : h1B;

    // ---- P1: h0c into LDS (prefetched regs for t>0), prev recovery, layer-0 GRU ----
    if (t == 0) stage(h0c);
    else        pfstore(pfH0);
    pfload(h1c, pfH1);                 // prefetch for P2b (h1c stable this step)
    if (tid < 32){
      float pv = 0.f;
      if (t > 0) pv = fmaxf(outac[(size_t)(t-1)*64 + b0 + tid] + S.bo2S, 0.f);
      S.prevS[tid] = pv;
      if (ng == 0 && t > 0) out[(size_t)(b0+tid)*TT + (t-1)] = pv;  // y[t-1]
    }
    __syncthreads();
    {
      float a0, a1, a2;
      dot3(S.Wh0, a0, a1, a2);
      if (p == 0){
        float pv  = S.prevS[bb];
        float ir  = S.gictx[(0*4+nl)*32+bb] + pv*S.wcol[0*4+nl];
        float iz  = S.gictx[(1*4+nl)*32+bb] + pv*S.wcol[1*4+nl];
        float inn = S.gictx[(2*4+nl)*32+bb] + pv*S.wcol[2*4+nl];
        float r  = sigm(ir + a0 + S.bhh0[0*4+nl]);
        float z  = sigm(iz + a1 + S.bhh0[1*4+nl]);
        float nn = tanhf(inn + r*(a2 + S.bhh0[2*4+nl]));
        float h0old = S.hbuf[bb*HPAD + (n0+nl)];
        h0n[(size_t)(b0+bb)*HH + n0 + nl] = (1.f - z)*nn + z*h0old;
      }
    }
    gbar(slots, w, tid, 3*t + 2);

    // ---- P2a: gi1 = h0n @ W_ih1.T ----
    stage(h0n);
    pfload(h0n, pfH0);                 // next step's h0c (same data, L1-hot)
    __syncthreads();
    {
      float a0, a1, a2;
      dot3(S.Wi1, a0, a1, a2);
      if (p == 0){
        S.gi1s[(0*4+nl)*32+bb] = a0 + S.bih1[0*4+nl];
        S.gi1s[(1*4+nl)*32+bb] = a1 + S.bih1[1*4+nl];
        S.gi1s[(2*4+nl)*32+bb] = a2 + S.bih1[2*4+nl];
      }
    }
    __syncthreads();
    // ---- P2b: gh1 = h1 @ W_hh1.T (h1c from prefetch regs), layer-1 GRU ----
    pfstore(pfH1);
    __syncthreads();
    {
      float a0, a1, a2;
      dot3(S.Wh1, a0, a1, a2);
      if (p == 0){
        float i1r = S.gi1s[(0*4+nl)*32+bb];
        float i1z = S.gi1s[(1*4+nl)*32+bb];
        float i1n = S.gi1s[(2*4+nl)*32+bb];
        float r1 = sigm(i1r + a0 + S.bhh1[0*4+nl]);
        float z1 = sigm(i1z + a1 + S.bhh1[1*4+nl]);
        float n1 = tanhf(i1n + r1*(a2 + S.bhh1[2*4+nl]));
        float h1old = S.hbuf[bb*HPAD + (n0+nl)];
        h1n[(size_t)(b0+bb)*HH + n0 + nl] = (1.f - z1)*n1 + z1*h1old;
      }
    }
    gbar(slots, w, tid, 3*t + 3);

    // ---- P3: y = relu(h1n @ W_o1.T + b_o1); partial out = wo2 . y ----
    if (tid < 32) S.outred[tid] = 0.f;
    stage(h1n);
    __syncthreads();
    {
      const float4* w4 = (const float4*)(S.Wo1) + nl*128;
      float s0 = 0.f;
      #pragma unroll 8
      for (int m = 0; m < 32; ++m){
        int idx = p + 4*m;
        float4 h4 = hb4[idx];
        float4 q0 = w4[idx];
        s0 += h4.x*q0.x + h4.y*q0.y + h4.z*q0.z + h4.w*q0.w;
      }
      s0 += __shfl_xor(s0,1); s0 += __shfl_xor(s0,2);
      if (p == 0){
        float y = fmaxf(s0 + S.bo1v[nl], 0.f);
        atomicAdd(&S.outred[bb], S.wo2v[nl]*y);
      }
    }
    __syncthreads();
    if (tid < 32)
      atomicAdd(&outac[(size_t)t*64 + b0 + tid], S.outred[tid]);
    gbar(slots, w, tid, 3*t + 4);
  }

  // ---- finale: y[1023] and final hidden states ----
  if (tid < 32 && ng == 0){
    float fv = fmaxf(outac[(size_t)1023*64 + b0 + tid] + S.bo2S, 0.f);
    out[(size_t)(b0+tid)*TT + 1023] = fv;
  }
  {
    // after t=1023 (odd), final states live in h0A / h1A
    int g = w*NT + tid;
    if (g < 32768)      out[65536 + g] = h0A[g];
    else if (g < 65536) out[65536 + g] = h1A[g - 32768];
  }
}

extern "C" void kernel_launch(void* const* d_in, const int* in_sizes, int n_in,
                              void* d_out, int out_size, void* d_ws, size_t ws_size,
                              hipStream_t stream){
  const float* ctx   = (const float*)d_in[0];
  const float* Wih0  = (const float*)d_in[2];
  const float* Whh0  = (const float*)d_in[3];
  const float* bih0  = (const float*)d_in[4];
  const float* bhh0  = (const float*)d_in[5];
  const float* Wih1  = (const float*)d_in[6];
  const float* Whh1  = (const float*)d_in[7];
  const float* bih1  = (const float*)d_in[8];
  const float* bhh1  = (const float*)d_in[9];
  const float* Wo1   = (const float*)d_in[10];
  const float* bo1   = (const float*)d_in[11];
  const float* Wo2   = (const float*)d_in[12];
  const float* bo2   = (const float*)d_in[13];

  (void)in_sizes; (void)n_in; (void)out_size; (void)ws_size;

  (void)hipFuncSetAttribute((const void*)decoder_rnn,
                            hipFuncAttributeMaxDynamicSharedMemorySize,
                            (int)sizeof(Smem));

  decoder_rnn<<<NWG, NT, sizeof(Smem), stream>>>(
      ctx, Wih0, Whh0, bih0, bhh0, Wih1, Whh1, bih1, bhh1,
      Wo1, bo1, Wo2, bo2, (float*)d_out, (float*)d_ws);
}

// Round 4
// 54991.400 us; speedup vs baseline: 1.1216x; 1.1216x over previous
//
#include <hip/hip_runtime.h>
#include <stdint.h>

// DecoderRNN: 2-layer GRU, H=512, B=64, T=1024, OUT=1, autoregressive scalar feedback.
// Persistent kernel: 256 WGs x 512 threads, 1 WG/CU, 3 single-level device barriers/step.
// R3: R1 structure + single-level epoch barrier + register prefetch done with NAMED
//     float4 variables (R2's pf[] arrays were address-taken via lambda pointer args ->
//     scratch spill -> 35 GB of WRITE_SIZE; named vars + unrolled macros force VGPRs).

#define HH   512
#define TT   1024
#define NWG  256
#define NT   512
#define HPAD 516   // hbuf row stride (floats)

struct __align__(16) Smem {
  float Wh0[12*HH];    // W_hh0 rows {g*512 + n0+nl}, layout [(g*4+nl)*512 + k]
  float Wi1[12*HH];
  float Wh1[12*HH];
  float Wo1[4*HH];
  float hbuf[32*HPAD]; // staged activation rows [bb][k], padded
  float gictx[12*32];
  float gi1s[12*32];
  float wcol[12];
  float bhh0[12];
  float bih1[12];
  float bhh1[12];
  float bo1v[4];
  float wo2v[4];
  float prevS[32];
  float outred[32];
  float bo2S;
};

__device__ __forceinline__ float sigm(float x){ return 1.f/(1.f + expf(-x)); }

// Single-level epoch barrier: every WG's wave0 polls all NWG slots.
// slots live in d_ws (0xAA poison is negative as int -> can't satisfy >= e).
__device__ __forceinline__ void gbar(int* slots, int w, int tid, int e){
  __syncthreads();
  if (tid == 0)
    __hip_atomic_store(&slots[w], e, __ATOMIC_RELEASE, __HIP_MEMORY_SCOPE_AGENT);
  if (tid < 64){
    for(;;){
      int m0 = __hip_atomic_load(&slots[tid*4+0], __ATOMIC_RELAXED, __HIP_MEMORY_SCOPE_AGENT);
      int m1 = __hip_atomic_load(&slots[tid*4+1], __ATOMIC_RELAXED, __HIP_MEMORY_SCOPE_AGENT);
      int m2 = __hip_atomic_load(&slots[tid*4+2], __ATOMIC_RELAXED, __HIP_MEMORY_SCOPE_AGENT);
      int m3 = __hip_atomic_load(&slots[tid*4+3], __ATOMIC_RELAXED, __HIP_MEMORY_SCOPE_AGENT);
      int mn = min(min(m0,m1), min(m2,m3));
      if (__all(mn >= e)) break;
      __builtin_amdgcn_s_sleep(1);
    }
    if (tid == 0)
      __builtin_amdgcn_fence(__ATOMIC_ACQUIRE, "agent");
  }
  __syncthreads();
}

// prefetch: 8 named float4 regs per buffer; fully unrolled, no address-taken storage
#define PF_DECL(P) float4 P##0, P##1, P##2, P##3, P##4, P##5, P##6, P##7;
#define PF_LOAD(src, P) { \
  const float4* s4_ = (const float4*)((src) + (size_t)b0 * HH); \
  P##0 = s4_[(0*4 + pr_r)*128 + pr_c]; \
  P##1 = s4_[(1*4 + pr_r)*128 + pr_c]; \
  P##2 = s4_[(2*4 + pr_r)*128 + pr_c]; \
  P##3 = s4_[(3*4 + pr_r)*128 + pr_c]; \
  P##4 = s4_[(4*4 + pr_r)*128 + pr_c]; \
  P##5 = s4_[(5*4 + pr_r)*128 + pr_c]; \
  P##6 = s4_[(6*4 + pr_r)*128 + pr_c]; \
  P##7 = s4_[(7*4 + pr_r)*128 + pr_c]; }
#define PF_STORE(P) { \
  *((float4*)(S.hbuf + (0*4 + pr_r)*HPAD) + pr_c) = P##0; \
  *((float4*)(S.hbuf + (1*4 + pr_r)*HPAD) + pr_c) = P##1; \
  *((float4*)(S.hbuf + (2*4 + pr_r)*HPAD) + pr_c) = P##2; \
  *((float4*)(S.hbuf + (3*4 + pr_r)*HPAD) + pr_c) = P##3; \
  *((float4*)(S.hbuf + (4*4 + pr_r)*HPAD) + pr_c) = P##4; \
  *((float4*)(S.hbuf + (5*4 + pr_r)*HPAD) + pr_c) = P##5; \
  *((float4*)(S.hbuf + (6*4 + pr_r)*HPAD) + pr_c) = P##6; \
  *((float4*)(S.hbuf + (7*4 + pr_r)*HPAD) + pr_c) = P##7; }

extern "C" __global__ void __launch_bounds__(NT, 2)
decoder_rnn(const float* __restrict__ ctx,   // [64][512]
            const float* __restrict__ Wih0,  // [1536][513]  (row stride 513)
            const float* __restrict__ Whh0,
            const float* __restrict__ bih0,
            const float* __restrict__ bhh0g,
            const float* __restrict__ Wih1,
            const float* __restrict__ Whh1,
            const float* __restrict__ bih1g,
            const float* __restrict__ bhh1g,
            const float* __restrict__ Wo1,
            const float* __restrict__ bo1g,
            const float* __restrict__ Wo2,
            const float* __restrict__ bo2g,
            float* __restrict__ out,         // [65536 outputs][65536 h_i]
            float* __restrict__ ws)
{
  extern __shared__ char smem_raw[];
  Smem& S = *reinterpret_cast<Smem*>(smem_raw);
  const int tid = threadIdx.x;
  const int w   = blockIdx.x;
  const int bg  = w >> 7, ng = w & 127;
  const int b0  = bg * 32, n0 = ng * 4;

  float* h0A   = ws;
  float* h0B   = ws + 32768;
  float* h1A   = ws + 65536;
  float* h1B   = ws + 98304;
  float* outac = ws + 131072;            // [1024][64] raw (pre-relu, pre-bias) sums
  int*   slots = (int*)(ws + 196608);

  // ---------------- init (all before first barrier) ----------------
  if (tid < 128){ h0A[w*128 + tid] = 0.f; h1A[w*128 + tid] = 0.f; }
  if (tid < 256) outac[w*256 + tid] = 0.f;

  for (int i = tid; i < 12*HH; i += NT){
    int rl = i >> 9, k = i & 511;
    int g = rl >> 2, nli = rl & 3;
    int grow = g*HH + n0 + nli;
    S.Wh0[i] = Whh0[(size_t)grow*HH + k];
    S.Wi1[i] = Wih1[(size_t)grow*HH + k];
    S.Wh1[i] = Whh1[(size_t)grow*HH + k];
  }
  for (int i = tid; i < 4*HH; i += NT){
    int nli = i >> 9, k = i & 511;
    S.Wo1[i] = Wo1[(size_t)(n0+nli)*HH + k];
  }
  if (tid < 12){
    int g = tid >> 2, nli = tid & 3;
    int grow = g*HH + n0 + nli;
    S.wcol[tid] = Wih0[(size_t)grow*513 + 512];
    S.bhh0[tid] = bhh0g[grow];
    S.bih1[tid] = bih1g[grow];
    S.bhh1[tid] = bhh1g[grow];
  }
  if (tid < 4){ S.bo1v[tid] = bo1g[n0+tid]; S.wo2v[tid] = Wo2[n0+tid]; }
  if (tid == 0) S.bo2S = bo2g[0];

  // gi_ctx = ctx @ W_ih0[:, :512].T + b_ih0 for our 12 rows x 32 batch (one-time)
  if (tid < 384){
    int rl = tid >> 5, bb = tid & 31;
    int g = rl >> 2, nli = rl & 3;
    int grow = g*HH + n0 + nli;
    const float* wr = Wih0 + (size_t)grow * 513;
    const float* cx = ctx  + (size_t)(b0+bb) * HH;
    float s = bih0[grow];
    for (int k = 0; k < HH; k += 4)
      s += wr[k]*cx[k] + wr[k+1]*cx[k+1] + wr[k+2]*cx[k+2] + wr[k+3]*cx[k+3];
    S.gictx[rl*32 + bb] = s;
  }

  gbar(slots, w, tid, 1);

  // per-thread dot mapping: 128 items (nl in [0,4), bb in [0,32)) x 4 K-parts
  const int p  = tid & 3;
  const int it = tid >> 2;
  const int bb = it & 31;
  const int nl = it >> 5;
  float4* hb4 = (float4*)(S.hbuf) + bb * (HPAD/4);

  // stage() item mapping for prefetch macros
  const int pr_r = tid >> 7;         // 0..3
  const int pr_c = tid & 127;

  // stage 32 rows x 512 floats from global into S.hbuf (padded)
  auto stage = [&](const float* src){
    const float4* s4 = (const float4*)(src + (size_t)b0 * HH);
    #pragma unroll
    for (int i = tid; i < 4096; i += NT){
      int r = i >> 7, c = i & 127;
      *((float4*)(S.hbuf + r*HPAD) + c) = s4[r*128 + c];
    }
  };

  // 3 gate-row dots of length 512 vs S.hbuf row bb; K split 4-way across p
  auto dot3 = [&](const float* Wbase, float& a0, float& a1, float& a2){
    const float4* w40 = (const float4*)Wbase + nl*128;
    const float4* w41 = w40 + 512;
    const float4* w42 = w41 + 512;
    float s0 = 0.f, s1 = 0.f, s2 = 0.f;
    #pragma unroll 8
    for (int m = 0; m < 32; ++m){
      int idx = p + 4*m;
      float4 h4 = hb4[idx];
      float4 q0 = w40[idx], q1 = w41[idx], q2 = w42[idx];
      s0 += h4.x*q0.x + h4.y*q0.y + h4.z*q0.z + h4.w*q0.w;
      s1 += h4.x*q1.x + h4.y*q1.y + h4.z*q1.z + h4.w*q1.w;
      s2 += h4.x*q2.x + h4.y*q2.y + h4.z*q2.z + h4.w*q2.w;
    }
    s0 += __shfl_xor(s0,1); s0 += __shfl_xor(s0,2);
    s1 += __shfl_xor(s1,1); s1 += __shfl_xor(s1,2);
    s2 += __shfl_xor(s2,1); s2 += __shfl_xor(s2,2);
    a0 = s0; a1 = s1; a2 = s2;
  };

  PF_DECL(A)   // h1c prefetch (issued P1, consumed P2b)
  PF_DECL(B)   // next-step h0c prefetch (issued P2a, consumed next P1)

  for (int t = 0; t < TT; ++t){
    const float* h0c = (t & 1) ? h0B : h0A;
    float*       h0n = (t & 1) ? h0A : h0B;
    const float* h1c = (t & 1) ? h1B : h1A;
    float*       h1n = (t & 1) ? h1A : h1B;

    // ---- P1: h0c into LDS (prefetched regs for t>0), prev recovery, layer-0 GRU ----
    if (t == 0) stage(h0c);
    else        PF_STORE(B)
    PF_LOAD(h1c, A)                    // for P2b (h1c stable & visible this step)
    if (tid < 32){
      float pv = 0.f;
      if (t > 0) pv = fmaxf(outac[(size_t)(t-1)*64 + b0 + tid] + S.bo2S, 0.f);
      S.prevS[tid] = pv;
      if (ng == 0 && t > 0) out[(size_t)(b0+tid)*TT + (t-1)] = pv;  // y[t-1]
    }
    __syncthreads();
    {
      float a0, a1, a2;
      dot3(S.Wh0, a0, a1, a2);
      if (p == 0){
        float pv  = S.prevS[bb];
        float ir  = S.gictx[(0*4+nl)*32+bb] + pv*S.wcol[0*4+nl];
        float iz  = S.gictx[(1*4+nl)*32+bb] + pv*S.wcol[1*4+nl];
        float inn = S.gictx[(2*4+nl)*32+bb] + pv*S.wcol[2*4+nl];
        float r  = sigm(ir + a0 + S.bhh0[0*4+nl]);
        float z  = sigm(iz + a1 + S.bhh0[1*4+nl]);
        float nn = tanhf(inn + r*(a2 + S.bhh0[2*4+nl]));
        float h0old = S.hbuf[bb*HPAD + (n0+nl)];
        h0n[(size_t)(b0+bb)*HH + n0 + nl] = (1.f - z)*nn + z*h0old;
      }
    }
    gbar(slots, w, tid, 3*t + 2);

    // ---- P2a: gi1 = h0n @ W_ih1.T ----
    stage(h0n);
    PF_LOAD(h0n, B)                    // next step's h0c (same data, L1-hot)
    __syncthreads();
    {
      float a0, a1, a2;
      dot3(S.Wi1, a0, a1, a2);
      if (p == 0){
        S.gi1s[(0*4+nl)*32+bb] = a0 + S.bih1[0*4+nl];
        S.gi1s[(1*4+nl)*32+bb] = a1 + S.bih1[1*4+nl];
        S.gi1s[(2*4+nl)*32+bb] = a2 + S.bih1[2*4+nl];
      }
    }
    __syncthreads();
    // ---- P2b: gh1 = h1 @ W_hh1.T (h1c from prefetch regs), layer-1 GRU ----
    PF_STORE(A)
    __syncthreads();
    {
      float a0, a1, a2;
      dot3(S.Wh1, a0, a1, a2);
      if (p == 0){
        float i1r = S.gi1s[(0*4+nl)*32+bb];
        float i1z = S.gi1s[(1*4+nl)*32+bb];
        float i1n = S.gi1s[(2*4+nl)*32+bb];
        float r1 = sigm(i1r + a0 + S.bhh1[0*4+nl]);
        float z1 = sigm(i1z + a1 + S.bhh1[1*4+nl]);
        float n1 = tanhf(i1n + r1*(a2 + S.bhh1[2*4+nl]));
        float h1old = S.hbuf[bb*HPAD + (n0+nl)];
        h1n[(size_t)(b0+bb)*HH + n0 + nl] = (1.f - z1)*n1 + z1*h1old;
      }
    }
    gbar(slots, w, tid, 3*t + 3);

    // ---- P3: y = relu(h1n @ W_o1.T + b_o1); partial out = wo2 . y ----
    if (tid < 32) S.outred[tid] = 0.f;
    stage(h1n);
    __syncthreads();
    {
      const float4* w4 = (const float4*)(S.Wo1) + nl*128;
      float s0 = 0.f;
      #pragma unroll 8
      for (int m = 0; m < 32; ++m){
        int idx = p + 4*m;
        float4 h4 = hb4[idx];
        float4 q0 = w4[idx];
        s0 += h4.x*q0.x + h4.y*q0.y + h4.z*q0.z + h4.w*q0.w;
      }
      s0 += __shfl_xor(s0,1); s0 += __shfl_xor(s0,2);
      if (p == 0){
        float y = fmaxf(s0 + S.bo1v[nl], 0.f);
        atomicAdd(&S.outred[bb], S.wo2v[nl]*y);
      }
    }
    __syncthreads();
    if (tid < 32)
      atomicAdd(&outac[(size_t)t*64 + b0 + tid], S.outred[tid]);
    gbar(slots, w, tid, 3*t + 4);
  }

  // ---- finale: y[1023] and final hidden states ----
  if (tid < 32 && ng == 0){
    float fv = fmaxf(outac[(size_t)1023*64 + b0 + tid] + S.bo2S, 0.f);
    out[(size_t)(b0+tid)*TT + 1023] = fv;
  }
  {
    // after t=1023 (odd), final states live in h0A / h1A
    int g = w*NT + tid;
    if (g < 32768)      out[65536 + g] = h0A[g];
    else if (g < 65536) out[65536 + g] = h1A[g - 32768];
  }
}

extern "C" void kernel_launch(void* const* d_in, const int* in_sizes, int n_in,
                              void* d_out, int out_size, void* d_ws, size_t ws_size,
                              hipStream_t stream){
  const float* ctx   = (const float*)d_in[0];
  const float* Wih0  = (const float*)d_in[2];
  const float* Whh0  = (const float*)d_in[3];
  const float* bih0  = (const float*)d_in[4];
  const float* bhh0  = (const float*)d_in[5];
  const float* Wih1  = (const float*)d_in[6];
  const float* Whh1  = (const float*)d_in[7];
  const float* bih1  = (const float*)d_in[8];
  const float* bhh1  = (const float*)d_in[9];
  const float* Wo1   = (const float*)d_in[10];
  const float* bo1   = (const float*)d_in[11];
  const float* Wo2   = (const float*)d_in[12];
  const float* bo2   = (const float*)d_in[13];

  (void)in_sizes; (void)n_in; (void)out_size; (void)ws_size;

  (void)hipFuncSetAttribute((const void*)decoder_rnn,
                            hipFuncAttributeMaxDynamicSharedMemorySize,
                            (int)sizeof(Smem));

  decoder_rnn<<<NWG, NT, sizeof(Smem), stream>>>(
      ctx, Wih0, Whh0, bih0, bhh0, Wih1, Whh1, bih1, bhh1,
      Wo1, bo1, Wo2, bo2, (float*)d_out, (float*)d_ws);
}

// Round 5
// 30847.665 us; speedup vs baseline: 1.9994x; 1.7827x over previous
//
#include <hip/hip_runtime.h>
#include <stdint.h>

// DecoderRNN R5: MFMA rewrite. 2-layer GRU, H=512, B=64, T=1024, scalar feedback.
// 128 WGs x 256 threads, phase-specialized:
//   WG  0-31 (j)   : phase A: h0n = GRU0(h0c, prev)      (Whh0 48x512 in LDS)
//   WG 32-63 (j-32): phase A: gh1raw = h1c @ Whh1^T      (Whh1 48x512 in LDS)
//   WG 64-95 (j-64): phase B: gi1 = h0n @ Wih1^T (regs) + gh1raw -> h1n
//   WG 96-127(j-96): phase C: y = relu(Wo1 h1n+b); partial wo2.y -> ring atomics
// Numerics: weights + h as bf16 hi/lo splits; 3 MFMAs (wh*hh + wh*hl + wl*hh)
// per K-tile accumulate in fp32 => ~2^-17 relative dot error (fp32-grade).
// Barrier: R1-proven two-level epoch barrier (master WG0), 128 participants.
// ws poison 0xAA is negative int -> slots need no init.

#define NWG 128
#define NT  256
#define TT  1024

typedef unsigned short ushort;
typedef unsigned int   uint;
typedef __attribute__((ext_vector_type(8))) short short8;
typedef __attribute__((ext_vector_type(4))) float f32x4;

struct __align__(16) Smem {
  ushort wpl[2][48*520];   // weight planes [hi|lo][row r=g*16+n][k], row stride 520 (16B-aligned, 2-way banks)
  float  gictx[3*16*68];   // A-L0: ctx@Wih0^T + bih0 (+bhh0 for r,z), [g][n][b] pad 68
  float  wcol[3][16];      // A-L0: Wih0[:,512] column
  float  bsumR[16], bsumZ[16]; // B: bih1+bhh1 for r,z
  float  binN[16];         // B: bih1 n-gate
  float  bhnN[16];         // B: bhh1 n-gate | A-L0: bhh0 n-gate
  float  bo1v[16], wo2v[16]; // C
};

__device__ __forceinline__ float sigm(float x){ return 1.f/(1.f + expf(-x)); }
__device__ __forceinline__ float bf2f(ushort h){ return __uint_as_float(((uint)h)<<16); }
__device__ __forceinline__ float hrec(ushort h, ushort l){ return bf2f(h)+bf2f(l); }
__device__ __forceinline__ ushort bfrnd(float x){
  uint u = __float_as_uint(x);
  return (ushort)((u + 0x7fffu + ((u>>16)&1u)) >> 16);
}

// Two-level epoch barrier (R1-proven). Master = WG0 wave0 (2 slots/lane).
__device__ __forceinline__ void gbar(int* slots, int* epoch, int w, int tid, int e){
  __syncthreads();
  if (tid == 0)
    __hip_atomic_store(&slots[w], e, __ATOMIC_RELEASE, __HIP_MEMORY_SCOPE_AGENT);
  if (w == 0 && tid < 64){
    for(;;){
      int m0 = __hip_atomic_load(&slots[tid*2+0], __ATOMIC_RELAXED, __HIP_MEMORY_SCOPE_AGENT);
      int m1 = __hip_atomic_load(&slots[tid*2+1], __ATOMIC_RELAXED, __HIP_MEMORY_SCOPE_AGENT);
      if (__all(min(m0,m1) >= e)) break;
      __builtin_amdgcn_s_sleep(1);
    }
    if (tid == 0){
      __builtin_amdgcn_fence(__ATOMIC_ACQUIRE, "agent");
      __hip_atomic_store(epoch, e, __ATOMIC_RELEASE, __HIP_MEMORY_SCOPE_AGENT);
    }
  }
  if (tid == 0){
    while (__hip_atomic_load(epoch, __ATOMIC_RELAXED, __HIP_MEMORY_SCOPE_AGENT) < e)
      __builtin_amdgcn_s_sleep(1);
    __builtin_amdgcn_fence(__ATOMIC_ACQUIRE, "agent");
  }
  __syncthreads();
}

extern "C" __global__ void __launch_bounds__(NT, 1)
decoder_rnn(const float* __restrict__ ctx,   // [64][512]
            const float* __restrict__ Wih0,  // [1536][513] (row stride 513!)
            const float* __restrict__ Whh0,  // [1536][512]
            const float* __restrict__ bih0,
            const float* __restrict__ bhh0g,
            const float* __restrict__ Wih1,
            const float* __restrict__ Whh1,
            const float* __restrict__ bih1g,
            const float* __restrict__ bhh1g,
            const float* __restrict__ Wo1,   // [512][512]
            const float* __restrict__ bo1g,
            const float* __restrict__ Wo2,   // [512]
            const float* __restrict__ bo2g,
            float* __restrict__ out,         // [64*1024 y][2*64*512 h_i]
            float* __restrict__ ws)
{
  extern __shared__ char smem_raw[];
  Smem& S = *reinterpret_cast<Smem*>(smem_raw);
  const int tid = threadIdx.x;
  const int wg  = blockIdx.x;

  // ws layout (bytes): h0hi[2][64*512]u16 | h0lo[2][..] | h1hi | h1lo |
  //                    gh1raw[32][3072]f32 | ring[2][64]f32 | slots[128] | epoch
  ushort* h0hi = (ushort*)ws;                 // 2 bufs x 32768
  ushort* h0lo = h0hi + 65536;
  ushort* h1hi = h0hi + 131072;               // 32768
  ushort* h1lo = h0hi + 163840;               // 32768
  float*  gh1raw = (float*)ws + 98304;        // 32*3072 floats
  float*  ring   = (float*)ws + 196608;       // 2*64 floats
  int*    slots  = (int*)((float*)ws + 196736);
  int*    epoch  = slots + NWG;

  const float bo2v = bo2g[0];

  // ---------------- init: zeros ----------------
  {
    uint* z;
    z = (uint*)h0hi; for (int i = wg*NT+tid; i < 16384; i += NWG*NT) z[i] = 0u;          // h0hi buf0
    z = (uint*)h0lo; for (int i = wg*NT+tid; i < 16384; i += NWG*NT) z[i] = 0u;          // h0lo buf0
    z = (uint*)h1hi; for (int i = wg*NT+tid; i < 32768; i += NWG*NT) z[i] = 0u;          // h1hi+h1lo (contig)
    if (wg == 0 && tid < 128) ring[tid] = 0.f;
  }

  // ---------------- init: weights -> LDS planes ----------------
  const int role = wg >> 5;          // 0:A-L0  1:A-G1  2:B  3:C
  const int j    = wg & 31;
  if (role == 0 || role == 1 || role == 2){
    const float* Wsrc = (role == 0) ? Whh0 : (role == 1) ? Whh1 : Wih1;
    for (int i = tid; i < 48*512; i += NT){
      int r = i >> 9, k = i & 511;
      int g = r >> 4, n = r & 15;
      float wv = Wsrc[(size_t)(g*512 + 16*j + n)*512 + k];
      ushort hh = bfrnd(wv);
      ushort ll = bfrnd(wv - bf2f(hh));
      S.wpl[0][r*520 + k] = hh;
      S.wpl[1][r*520 + k] = ll;
    }
  } else {
    for (int i = tid; i < 16*512; i += NT){
      int r = i >> 9, k = i & 511;
      float wv = Wo1[(size_t)(16*j + r)*512 + k];
      ushort hh = bfrnd(wv);
      ushort ll = bfrnd(wv - bf2f(hh));
      S.wpl[0][r*520 + k] = hh;
      S.wpl[1][r*520 + k] = ll;
    }
    if (tid < 16){ S.bo1v[tid] = bo1g[16*j + tid]; S.wo2v[tid] = Wo2[16*j + tid]; }
  }
  if (role == 0){
    if (tid < 48){
      int g = tid >> 4, n = tid & 15;
      S.wcol[g][n] = Wih0[(size_t)(g*512 + 16*j + n)*513 + 512];
    }
    if (tid < 16) S.bhnN[tid] = bhh0g[2*512 + 16*j + tid];
    // gictx[g][n][b] = ctx[b] . Wih0_row + bih0 (+bhh0 for r,z)
    for (int idx = tid; idx < 3072; idx += NT){
      int r = idx >> 6, b = idx & 63;
      int g = r >> 4, n = r & 15;
      int grow = g*512 + 16*j + n;
      const float* wr = Wih0 + (size_t)grow*513;
      const float* cx = ctx  + (size_t)b*512;
      float s = bih0[grow];
      if (g < 2) s += bhh0g[grow];
      #pragma unroll 4
      for (int k = 0; k < 512; ++k) s += wr[k]*cx[k];
      S.gictx[g*1088 + n*68 + b] = s;
    }
  }
  if (role == 2 && tid < 16){
    int n = tid;
    S.bsumR[n] = bih1g[0*512 + 16*j + n] + bhh1g[0*512 + 16*j + n];
    S.bsumZ[n] = bih1g[1*512 + 16*j + n] + bhh1g[1*512 + 16*j + n];
    S.binN[n]  = bih1g[2*512 + 16*j + n];
    S.bhnN[n]  = bhh1g[2*512 + 16*j + n];
  }

  gbar(slots, epoch, wg, tid, 1);

  // lane roles
  const int v   = tid >> 6;       // wave = M-tile (batches 16v..16v+16)
  const int l   = tid & 63;
  const int q   = l >> 4;
  const int col = l & 15;
  const int aoff = (16*v + col)*512 + q*8;   // A-frag: h[b=16v+col][k=kt*32+q*8 ..+8]
  const int b0w  = 16*v + 4*q;               // C rows: b = b0w + i
  const int ng   = 16*j + col;               // this WG's global neuron col

  for (int t = 0; t < TT; ++t){
    const int r0 = t & 1, w0 = r0 ^ 1;

    // ================= phase A =================
    if (role == 0){
      if (wg == 1 && tid < 16)   // zero the ring slot phase C will accumulate into
        *(f32x4*)(ring + (t&1)*64 + tid*4) = f32x4{0.f,0.f,0.f,0.f};
      if (wg == 0 && t > 0 && tid < 64)
        out[(size_t)tid*TT + (t-1)] = fmaxf(ring[((t-1)&1)*64 + tid] + bo2v, 0.f);

      const ushort* rH = h0hi + r0*32768;
      const ushort* rL = h0lo + r0*32768;
      f32x4 acc[3] = {{0,0,0,0},{0,0,0,0},{0,0,0,0}};
      #pragma unroll
      for (int kt = 0; kt < 16; ++kt){
        short8 ah = *(const short8*)(rH + aoff + kt*32);
        short8 al = *(const short8*)(rL + aoff + kt*32);
        #pragma unroll
        for (int g = 0; g < 3; ++g){
          int wo = (g*16 + col)*520 + kt*32 + q*8;
          short8 bh = *(const short8*)(&S.wpl[0][wo]);
          short8 bl = *(const short8*)(&S.wpl[1][wo]);
          acc[g] = __builtin_amdgcn_mfma_f32_16x16x32_bf16(ah, bh, acc[g], 0, 0, 0);
          acc[g] = __builtin_amdgcn_mfma_f32_16x16x32_bf16(al, bh, acc[g], 0, 0, 0);
          acc[g] = __builtin_amdgcn_mfma_f32_16x16x32_bf16(ah, bl, acc[g], 0, 0, 0);
        }
      }
      f32x4 pv4 = {0,0,0,0};
      if (t > 0){
        f32x4 pr = *(const f32x4*)(ring + ((t-1)&1)*64 + b0w);
        #pragma unroll
        for (int i = 0; i < 4; ++i) pv4[i] = fmaxf(pr[i] + bo2v, 0.f);
      }
      f32x4 gR = *(const f32x4*)&S.gictx[0*1088 + col*68 + b0w];
      f32x4 gZ = *(const f32x4*)&S.gictx[1*1088 + col*68 + b0w];
      f32x4 gN = *(const f32x4*)&S.gictx[2*1088 + col*68 + b0w];
      float wc0 = S.wcol[0][col], wc1 = S.wcol[1][col], wc2 = S.wcol[2][col];
      float bhn = S.bhnN[col];
      ushort* wH = h0hi + w0*32768;
      ushort* wL = h0lo + w0*32768;
      #pragma unroll
      for (int i = 0; i < 4; ++i){
        int b = b0w + i;
        float hold = hrec(rH[b*512 + ng], rL[b*512 + ng]);
        float rr = sigm(gR[i] + pv4[i]*wc0 + acc[0][i]);
        float zz = sigm(gZ[i] + pv4[i]*wc1 + acc[1][i]);
        float nn = tanhf(gN[i] + pv4[i]*wc2 + rr*(acc[2][i] + bhn));
        float h  = (1.f - zz)*nn + zz*hold;
        ushort hh = bfrnd(h);
        wH[b*512 + ng] = hh;
        wL[b*512 + ng] = bfrnd(h - bf2f(hh));
      }
    } else if (role == 1){
      f32x4 acc[3] = {{0,0,0,0},{0,0,0,0},{0,0,0,0}};
      #pragma unroll
      for (int kt = 0; kt < 16; ++kt){
        short8 ah = *(const short8*)(h1hi + aoff + kt*32);
        short8 al = *(const short8*)(h1lo + aoff + kt*32);
        #pragma unroll
        for (int g = 0; g < 3; ++g){
          int wo = (g*16 + col)*520 + kt*32 + q*8;
          short8 bh = *(const short8*)(&S.wpl[0][wo]);
          short8 bl = *(const short8*)(&S.wpl[1][wo]);
          acc[g] = __builtin_amdgcn_mfma_f32_16x16x32_bf16(ah, bh, acc[g], 0, 0, 0);
          acc[g] = __builtin_amdgcn_mfma_f32_16x16x32_bf16(al, bh, acc[g], 0, 0, 0);
          acc[g] = __builtin_amdgcn_mfma_f32_16x16x32_bf16(ah, bl, acc[g], 0, 0, 0);
        }
      }
      float* gp = gh1raw + (size_t)j*3072;
      #pragma unroll
      for (int g = 0; g < 3; ++g)
        *(f32x4*)(gp + g*1024 + v*256 + l*4) = acc[g];
    }
    gbar(slots, epoch, wg, tid, 3*t + 2);

    // ================= phase B =================
    if (role == 2){
      const ushort* rH = h0hi + w0*32768;     // h0n
      const ushort* rL = h0lo + w0*32768;
      f32x4 acc[3] = {{0,0,0,0},{0,0,0,0},{0,0,0,0}};
      #pragma unroll
      for (int kt = 0; kt < 16; ++kt){
        short8 ah = *(const short8*)(rH + aoff + kt*32);
        short8 al = *(const short8*)(rL + aoff + kt*32);
        #pragma unroll
        for (int g = 0; g < 3; ++g){
          int wo = (g*16 + col)*520 + kt*32 + q*8;
          short8 bh = *(const short8*)(&S.wpl[0][wo]);
          short8 bl = *(const short8*)(&S.wpl[1][wo]);
          acc[g] = __builtin_amdgcn_mfma_f32_16x16x32_bf16(ah, bh, acc[g], 0, 0, 0);
          acc[g] = __builtin_amdgcn_mfma_f32_16x16x32_bf16(al, bh, acc[g], 0, 0, 0);
          acc[g] = __builtin_amdgcn_mfma_f32_16x16x32_bf16(ah, bl, acc[g], 0, 0, 0);
        }
      }
      const float* gp = gh1raw + (size_t)j*3072;
      f32x4 hR = *(const f32x4*)(gp + 0*1024 + v*256 + l*4);
      f32x4 hZ = *(const f32x4*)(gp + 1*1024 + v*256 + l*4);
      f32x4 hN = *(const f32x4*)(gp + 2*1024 + v*256 + l*4);
      float bsR = S.bsumR[col], bsZ = S.bsumZ[col], biN = S.binN[col], bhN = S.bhnN[col];
      #pragma unroll
      for (int i = 0; i < 4; ++i){
        int b = b0w + i;
        float hold = hrec(h1hi[b*512 + ng], h1lo[b*512 + ng]);
        float r1 = sigm(acc[0][i] + hR[i] + bsR);
        float z1 = sigm(acc[1][i] + hZ[i] + bsZ);
        float n1 = tanhf(acc[2][i] + biN + r1*(hN[i] + bhN));
        float h  = (1.f - z1)*n1 + z1*hold;
        ushort hh = bfrnd(h);
        h1hi[b*512 + ng] = hh;
        h1lo[b*512 + ng] = bfrnd(h - bf2f(hh));
      }
    }
    gbar(slots, epoch, wg, tid, 3*t + 3);

    // ================= phase C =================
    if (role == 3){
      f32x4 acc = {0,0,0,0};
      #pragma unroll
      for (int kt = 0; kt < 16; ++kt){
        short8 ah = *(const short8*)(h1hi + aoff + kt*32);
        short8 al = *(const short8*)(h1lo + aoff + kt*32);
        int wo = col*520 + kt*32 + q*8;
        short8 bh = *(const short8*)(&S.wpl[0][wo]);
        short8 bl = *(const short8*)(&S.wpl[1][wo]);
        acc = __builtin_amdgcn_mfma_f32_16x16x32_bf16(ah, bh, acc, 0, 0, 0);
        acc = __builtin_amdgcn_mfma_f32_16x16x32_bf16(al, bh, acc, 0, 0, 0);
        acc = __builtin_amdgcn_mfma_f32_16x16x32_bf16(ah, bl, acc, 0, 0, 0);
      }
      float s0 = S.wo2v[col]*fmaxf(acc[0] + S.bo1v[col], 0.f);
      float s1 = S.wo2v[col]*fmaxf(acc[1] + S.bo1v[col], 0.f);
      float s2 = S.wo2v[col]*fmaxf(acc[2] + S.bo1v[col], 0.f);
      float s3 = S.wo2v[col]*fmaxf(acc[3] + S.bo1v[col], 0.f);
      #pragma unroll
      for (int d = 1; d < 16; d <<= 1){
        s0 += __shfl_xor(s0, d);
        s1 += __shfl_xor(s1, d);
        s2 += __shfl_xor(s2, d);
        s3 += __shfl_xor(s3, d);
      }
      if (col == 0){
        float* rp = ring + (t&1)*64 + b0w;
        atomicAdd(rp + 0, s0);
        atomicAdd(rp + 1, s1);
        atomicAdd(rp + 2, s2);
        atomicAdd(rp + 3, s3);
      }
    }
    gbar(slots, epoch, wg, tid, 3*t + 4);
  }

  // ---------------- finale ----------------
  if (wg == 0 && tid < 64)
    out[(size_t)tid*TT + 1023] = fmaxf(ring[(1023&1)*64 + tid] + bo2v, 0.f);
  // final h_i: h0 planes buf0 (t=1023 wrote w0=0), h1 planes
  #pragma unroll
  for (int k = 0; k < 2; ++k){
    int g = wg*512 + k*256 + tid;     // [0, 65536)
    if (g < 32768) out[65536 + g] = hrec(h0hi[g], h0lo[g]);            // layer 0
    else           out[65536 + g] = hrec(h1hi[g-32768], h1lo[g-32768]); // layer 1
  }
}

extern "C" void kernel_launch(void* const* d_in, const int* in_sizes, int n_in,
                              void* d_out, int out_size, void* d_ws, size_t ws_size,
                              hipStream_t stream){
  const float* ctx   = (const float*)d_in[0];
  const float* Wih0  = (const float*)d_in[2];
  const float* Whh0  = (const float*)d_in[3];
  const float* bih0  = (const float*)d_in[4];
  const float* bhh0  = (const float*)d_in[5];
  const float* Wih1  = (const float*)d_in[6];
  const float* Whh1  = (const float*)d_in[7];
  const float* bih1  = (const float*)d_in[8];
  const float* bhh1  = (const float*)d_in[9];
  const float* Wo1   = (const float*)d_in[10];
  const float* bo1   = (const float*)d_in[11];
  const float* Wo2   = (const float*)d_in[12];
  const float* bo2   = (const float*)d_in[13];

  (void)in_sizes; (void)n_in; (void)out_size; (void)ws_size;

  (void)hipFuncSetAttribute((const void*)decoder_rnn,
                            hipFuncAttributeMaxDynamicSharedMemorySize,
                            (int)sizeof(Smem));

  decoder_rnn<<<NWG, NT, sizeof(Smem), stream>>>(
      ctx, Wih0, Whh0, bih0, bhh0, Wih1, Whh1, bih1, bhh1,
      Wo1, bo1, Wo2, bo2, (float*)d_out, (float*)d_ws);
}

// Round 6
// 28518.015 us; speedup vs baseline: 2.1627x; 1.0817x over previous
//
#include <hip/hip_runtime.h>
#include <stdint.h>

// DecoderRNN R6: MFMA + fully pre-issued loads. 2-layer GRU, H=512, B=64, T=1024.
// 128 WGs x 256 threads, phase-specialized (role = wg>>5, j = wg&31):
//   role 0: phase A: h0n = GRU0(h0c, prev);  also reduces yout partials -> prev
//   role 1: phase A: gh1raw = h1c @ Whh1^T
//   role 2: phase B: h1n = GRU1(gi1 = h0n @ Wih1^T, gh1raw, h1c)
//   role 3: phase C: y-partials: wo2 . relu(Wo1 h1n + bo1) -> yout scratch
// Numerics: weights + h as bf16 hi/lo planes; 3 MFMAs/K-tile, fp32 accum.
// All global loads in each phase are issued into NAMED registers before the
// MFMA chain (one LLC RTT instead of 16 serialized) — R5 was latency-bound
// with VGPR=68. Two-level epoch barrier (master WG0), 3/step.

#define NWG 128
#define NT  256
#define TT  1024

typedef unsigned short ushort;
typedef unsigned int   uint;
typedef __attribute__((ext_vector_type(8))) short short8;
typedef __attribute__((ext_vector_type(4))) float f32x4;

struct __align__(16) Smem {
  ushort wpl[2][48*520];   // [hi|lo][row r=g*16+n][k], row stride 520
  float  gictx[3*16*68];   // role0: ctx@Wih0^T + bih0 (+bhh0 r,z), [g][n][b] pad 68
  float  wcol[3][16];      // role0: Wih0[:,512]
  float  bsumR[16], bsumZ[16], binN[16], bhnN[16];
  float  bo1v[16], wo2v[16];
  float  prevS[64];
};

__device__ __forceinline__ float sigm(float x){ return 1.f/(1.f + expf(-x)); }
__device__ __forceinline__ float bf2f(ushort h){ return __uint_as_float(((uint)h)<<16); }
__device__ __forceinline__ ushort bfrnd(float x){
  uint u = __float_as_uint(x);
  return (ushort)((u + 0x7fffu + ((u>>16)&1u)) >> 16);
}

__device__ __forceinline__ void gbar(int* slots, int* epoch, int w, int tid, int e){
  __syncthreads();
  if (tid == 0)
    __hip_atomic_store(&slots[w], e, __ATOMIC_RELEASE, __HIP_MEMORY_SCOPE_AGENT);
  if (w == 0 && tid < 64){
    for(;;){
      int m0 = __hip_atomic_load(&slots[tid*2+0], __ATOMIC_RELAXED, __HIP_MEMORY_SCOPE_AGENT);
      int m1 = __hip_atomic_load(&slots[tid*2+1], __ATOMIC_RELAXED, __HIP_MEMORY_SCOPE_AGENT);
      if (__all(min(m0,m1) >= e)) break;
      __builtin_amdgcn_s_sleep(1);
    }
    if (tid == 0){
      __builtin_amdgcn_fence(__ATOMIC_ACQUIRE, "agent");
      __hip_atomic_store(epoch, e, __ATOMIC_RELEASE, __HIP_MEMORY_SCOPE_AGENT);
    }
  }
  if (tid == 0){
    while (__hip_atomic_load(epoch, __ATOMIC_RELAXED, __HIP_MEMORY_SCOPE_AGENT) < e)
      __builtin_amdgcn_s_sleep(1);
    __builtin_amdgcn_fence(__ATOMIC_ACQUIRE, "agent");
  }
  __syncthreads();
}

// ---- named-register A-fragment preload (no arrays -> no scratch spill) ----
#define LD8(P, i) (*(const short8*)((P) + aoff + (i)*32))
#define DECL_A(PH, PL) \
  short8 ah0=LD8(PH,0), ah1=LD8(PH,1), ah2=LD8(PH,2), ah3=LD8(PH,3), \
         ah4=LD8(PH,4), ah5=LD8(PH,5), ah6=LD8(PH,6), ah7=LD8(PH,7), \
         ah8=LD8(PH,8), ah9=LD8(PH,9), ah10=LD8(PH,10), ah11=LD8(PH,11), \
         ah12=LD8(PH,12), ah13=LD8(PH,13), ah14=LD8(PH,14), ah15=LD8(PH,15); \
  short8 al0=LD8(PL,0), al1=LD8(PL,1), al2=LD8(PL,2), al3=LD8(PL,3), \
         al4=LD8(PL,4), al5=LD8(PL,5), al6=LD8(PL,6), al7=LD8(PL,7), \
         al8=LD8(PL,8), al9=LD8(PL,9), al10=LD8(PL,10), al11=LD8(PL,11), \
         al12=LD8(PL,12), al13=LD8(PL,13), al14=LD8(PL,14), al15=LD8(PL,15);

#define MS3(i, AH, AL) { \
  const int ko_ = (i)*32 + q*8; \
  short8 bh_ = *(const short8*)(&S.wpl[0][(col)*520 + ko_]); \
  short8 bl_ = *(const short8*)(&S.wpl[1][(col)*520 + ko_]); \
  acc0 = __builtin_amdgcn_mfma_f32_16x16x32_bf16(AH, bh_, acc0, 0,0,0); \
  acc0 = __builtin_amdgcn_mfma_f32_16x16x32_bf16(AL, bh_, acc0, 0,0,0); \
  acc0 = __builtin_amdgcn_mfma_f32_16x16x32_bf16(AH, bl_, acc0, 0,0,0); \
  bh_ = *(const short8*)(&S.wpl[0][(16+col)*520 + ko_]); \
  bl_ = *(const short8*)(&S.wpl[1][(16+col)*520 + ko_]); \
  acc1 = __builtin_amdgcn_mfma_f32_16x16x32_bf16(AH, bh_, acc1, 0,0,0); \
  acc1 = __builtin_amdgcn_mfma_f32_16x16x32_bf16(AL, bh_, acc1, 0,0,0); \
  acc1 = __builtin_amdgcn_mfma_f32_16x16x32_bf16(AH, bl_, acc1, 0,0,0); \
  bh_ = *(const short8*)(&S.wpl[0][(32+col)*520 + ko_]); \
  bl_ = *(const short8*)(&S.wpl[1][(32+col)*520 + ko_]); \
  acc2 = __builtin_amdgcn_mfma_f32_16x16x32_bf16(AH, bh_, acc2, 0,0,0); \
  acc2 = __builtin_amdgcn_mfma_f32_16x16x32_bf16(AL, bh_, acc2, 0,0,0); \
  acc2 = __builtin_amdgcn_mfma_f32_16x16x32_bf16(AH, bl_, acc2, 0,0,0); }

#define MS1(i, AH, AL) { \
  const int ko_ = (i)*32 + q*8; \
  short8 bh_ = *(const short8*)(&S.wpl[0][(col)*520 + ko_]); \
  short8 bl_ = *(const short8*)(&S.wpl[1][(col)*520 + ko_]); \
  acc0 = __builtin_amdgcn_mfma_f32_16x16x32_bf16(AH, bh_, acc0, 0,0,0); \
  acc0 = __builtin_amdgcn_mfma_f32_16x16x32_bf16(AL, bh_, acc0, 0,0,0); \
  acc0 = __builtin_amdgcn_mfma_f32_16x16x32_bf16(AH, bl_, acc0, 0,0,0); }

#define RUN16(M) M(0,ah0,al0) M(1,ah1,al1) M(2,ah2,al2) M(3,ah3,al3) \
                 M(4,ah4,al4) M(5,ah5,al5) M(6,ah6,al6) M(7,ah7,al7) \
                 M(8,ah8,al8) M(9,ah9,al9) M(10,ah10,al10) M(11,ah11,al11) \
                 M(12,ah12,al12) M(13,ah13,al13) M(14,ah14,al14) M(15,ah15,al15)

extern "C" __global__ void __launch_bounds__(NT, 1)
decoder_rnn(const float* __restrict__ ctx,   // [64][512]
            const float* __restrict__ Wih0,  // [1536][513] (row stride 513!)
            const float* __restrict__ Whh0,
            const float* __restrict__ bih0,
            const float* __restrict__ bhh0g,
            const float* __restrict__ Wih1,
            const float* __restrict__ Whh1,
            const float* __restrict__ bih1g,
            const float* __restrict__ bhh1g,
            const float* __restrict__ Wo1,
            const float* __restrict__ bo1g,
            const float* __restrict__ Wo2,
            const float* __restrict__ bo2g,
            float* __restrict__ out,         // [64*1024 y][65536 h_i]
            float* __restrict__ ws)
{
  extern __shared__ char smem_raw[];
  Smem& S = *reinterpret_cast<Smem*>(smem_raw);
  const int tid = threadIdx.x;
  const int wg  = blockIdx.x;

  ushort* h0hi = (ushort*)ws;                 // 2 bufs x 32768
  ushort* h0lo = h0hi + 65536;
  ushort* h1hi = h0hi + 131072;               // 32768
  ushort* h1lo = h0hi + 163840;               // 32768
  float*  gh1raw = (float*)ws + 98304;        // 32*3072 floats
  float*  yout   = (float*)ws + 196608;       // 2 parities x 32 j x 64 b
  int*    slots  = (int*)((float*)ws + 200704);
  int*    epoch  = slots + NWG;

  const float bo2v = bo2g[0];

  // ---------------- init: zeros ----------------
  {
    uint* z;
    z = (uint*)h0hi; for (int i = wg*NT+tid; i < 16384; i += NWG*NT) z[i] = 0u;
    z = (uint*)h0lo; for (int i = wg*NT+tid; i < 16384; i += NWG*NT) z[i] = 0u;
    z = (uint*)h1hi; for (int i = wg*NT+tid; i < 32768; i += NWG*NT) z[i] = 0u;
  }

  // ---------------- init: weights -> LDS planes ----------------
  const int role = wg >> 5;
  const int j    = wg & 31;
  if (role != 3){
    const float* Wsrc = (role == 0) ? Whh0 : (role == 1) ? Whh1 : Wih1;
    for (int i = tid; i < 48*512; i += NT){
      int r = i >> 9, k = i & 511;
      int g = r >> 4, n = r & 15;
      float wv = Wsrc[(size_t)(g*512 + 16*j + n)*512 + k];
      ushort hh = bfrnd(wv);
      S.wpl[0][r*520 + k] = hh;
      S.wpl[1][r*520 + k] = bfrnd(wv - bf2f(hh));
    }
  } else {
    for (int i = tid; i < 16*512; i += NT){
      int r = i >> 9, k = i & 511;
      float wv = Wo1[(size_t)(16*j + r)*512 + k];
      ushort hh = bfrnd(wv);
      S.wpl[0][r*520 + k] = hh;
      S.wpl[1][r*520 + k] = bfrnd(wv - bf2f(hh));
    }
    if (tid < 16){ S.bo1v[tid] = bo1g[16*j + tid]; S.wo2v[tid] = Wo2[16*j + tid]; }
  }
  if (role == 0){
    if (tid < 48){
      int g = tid >> 4, n = tid & 15;
      S.wcol[g][n] = Wih0[(size_t)(g*512 + 16*j + n)*513 + 512];
    }
    if (tid < 16) S.bhnN[tid] = bhh0g[2*512 + 16*j + tid];
    for (int idx = tid; idx < 3072; idx += NT){
      int r = idx >> 6, b = idx & 63;
      int g = r >> 4, n = r & 15;
      int grow = g*512 + 16*j + n;
      const float* wr = Wih0 + (size_t)grow*513;
      const float* cx = ctx  + (size_t)b*512;
      float s = bih0[grow];
      if (g < 2) s += bhh0g[grow];
      #pragma unroll 4
      for (int k = 0; k < 512; ++k) s += wr[k]*cx[k];
      S.gictx[g*1088 + n*68 + b] = s;
    }
  }
  if (role == 2 && tid < 16){
    int n = tid;
    S.bsumR[n] = bih1g[16*j + n]         + bhh1g[16*j + n];
    S.bsumZ[n] = bih1g[512 + 16*j + n]   + bhh1g[512 + 16*j + n];
    S.binN[n]  = bih1g[1024 + 16*j + n];
    S.bhnN[n]  = bhh1g[1024 + 16*j + n];
  }

  gbar(slots, epoch, wg, tid, 1);

  const int v   = tid >> 6;
  const int l   = tid & 63;
  const int q   = l >> 4;
  const int col = l & 15;
  const int aoff = (16*v + col)*512 + q*8;
  const int b0w  = 16*v + 4*q;
  const int ng   = 16*j + col;

  for (int t = 0; t < TT; ++t){
    const int r0 = t & 1, w0 = r0 ^ 1;

    // ================= phase A =================
    if (role == 0){
      const ushort* rH = h0hi + r0*32768;
      const ushort* rL = h0lo + r0*32768;
      f32x4 acc0={0,0,0,0}, acc1={0,0,0,0}, acc2={0,0,0,0};
      DECL_A(rH, rL)
      ushort ph0=rH[(b0w+0)*512+ng], ph1=rH[(b0w+1)*512+ng],
             ph2=rH[(b0w+2)*512+ng], ph3=rH[(b0w+3)*512+ng];
      ushort pl0=rL[(b0w+0)*512+ng], pl1=rL[(b0w+1)*512+ng],
             pl2=rL[(b0w+2)*512+ng], pl3=rL[(b0w+3)*512+ng];
      if (tid < 64){
        float s = 0.f;
        if (t > 0){
          const float* yp = yout + ((t-1)&1)*2048 + tid;
          #pragma unroll
          for (int jj = 0; jj < 32; ++jj) s += yp[jj*64];
        }
        float pv = fmaxf(s + bo2v, 0.f);
        S.prevS[tid] = pv;
        if (wg == 0 && t > 0) out[(size_t)tid*TT + (t-1)] = pv;
      }
      RUN16(MS3)
      __syncthreads();
      f32x4 pv4 = *(const f32x4*)&S.prevS[b0w];
      f32x4 gR = *(const f32x4*)&S.gictx[0*1088 + col*68 + b0w];
      f32x4 gZ = *(const f32x4*)&S.gictx[1*1088 + col*68 + b0w];
      f32x4 gN = *(const f32x4*)&S.gictx[2*1088 + col*68 + b0w];
      float wc0 = S.wcol[0][col], wc1 = S.wcol[1][col], wc2 = S.wcol[2][col];
      float bhn = S.bhnN[col];
      ushort* wH = h0hi + w0*32768;
      ushort* wL = h0lo + w0*32768;
      #define E0(i, PH, PL) { \
        float hold = bf2f(PH) + bf2f(PL); \
        float rr = sigm(gR[i] + pv4[i]*wc0 + acc0[i]); \
        float zz = sigm(gZ[i] + pv4[i]*wc1 + acc1[i]); \
        float nn = tanhf(gN[i] + pv4[i]*wc2 + rr*(acc2[i] + bhn)); \
        float h = (1.f-zz)*nn + zz*hold; \
        ushort hb = bfrnd(h); \
        wH[(size_t)(b0w+(i))*512 + ng] = hb; \
        wL[(size_t)(b0w+(i))*512 + ng] = bfrnd(h - bf2f(hb)); }
      E0(0,ph0,pl0) E0(1,ph1,pl1) E0(2,ph2,pl2) E0(3,ph3,pl3)
      #undef E0
    } else if (role == 1){
      f32x4 acc0={0,0,0,0}, acc1={0,0,0,0}, acc2={0,0,0,0};
      DECL_A(h1hi, h1lo)
      RUN16(MS3)
      float* gp = gh1raw + (size_t)j*3072 + v*256 + l*4;
      *(f32x4*)(gp + 0)    = acc0;
      *(f32x4*)(gp + 1024) = acc1;
      *(f32x4*)(gp + 2048) = acc2;
    }
    gbar(slots, epoch, wg, tid, 3*t + 2);

    // ================= phase B =================
    if (role == 2){
      const ushort* rH = h0hi + w0*32768;
      const ushort* rL = h0lo + w0*32768;
      f32x4 acc0={0,0,0,0}, acc1={0,0,0,0}, acc2={0,0,0,0};
      DECL_A(rH, rL)
      const float* gp = gh1raw + (size_t)j*3072 + v*256 + l*4;
      f32x4 hR = *(const f32x4*)(gp + 0);
      f32x4 hZ = *(const f32x4*)(gp + 1024);
      f32x4 hN = *(const f32x4*)(gp + 2048);
      ushort ph0=h1hi[(b0w+0)*512+ng], ph1=h1hi[(b0w+1)*512+ng],
             ph2=h1hi[(b0w+2)*512+ng], ph3=h1hi[(b0w+3)*512+ng];
      ushort pl0=h1lo[(b0w+0)*512+ng], pl1=h1lo[(b0w+1)*512+ng],
             pl2=h1lo[(b0w+2)*512+ng], pl3=h1lo[(b0w+3)*512+ng];
      RUN16(MS3)
      float bsR = S.bsumR[col], bsZ = S.bsumZ[col], biN = S.binN[col], bhN = S.bhnN[col];
      #define E1(i, PH, PL) { \
        float hold = bf2f(PH) + bf2f(PL); \
        float r1 = sigm(acc0[i] + hR[i] + bsR); \
        float z1 = sigm(acc1[i] + hZ[i] + bsZ); \
        float n1 = tanhf(acc2[i] + biN + r1*(hN[i] + bhN)); \
        float h = (1.f-z1)*n1 + z1*hold; \
        ushort hb = bfrnd(h); \
        h1hi[(size_t)(b0w+(i))*512 + ng] = hb; \
        h1lo[(size_t)(b0w+(i))*512 + ng] = bfrnd(h - bf2f(hb)); }
      E1(0,ph0,pl0) E1(1,ph1,pl1) E1(2,ph2,pl2) E1(3,ph3,pl3)
      #undef E1
    }
    gbar(slots, epoch, wg, tid, 3*t + 3);

    // ================= phase C =================
    if (role == 3){
      f32x4 acc0={0,0,0,0};
      DECL_A(h1hi, h1lo)
      RUN16(MS1)
      float s0 = S.wo2v[col]*fmaxf(acc0[0] + S.bo1v[col], 0.f);
      float s1 = S.wo2v[col]*fmaxf(acc0[1] + S.bo1v[col], 0.f);
      float s2 = S.wo2v[col]*fmaxf(acc0[2] + S.bo1v[col], 0.f);
      float s3 = S.wo2v[col]*fmaxf(acc0[3] + S.bo1v[col], 0.f);
      #pragma unroll
      for (int d = 1; d < 16; d <<= 1){
        s0 += __shfl_xor(s0, d);
        s1 += __shfl_xor(s1, d);
        s2 += __shfl_xor(s2, d);
        s3 += __shfl_xor(s3, d);
      }
      if (col == 0)
        *(f32x4*)(yout + (t&1)*2048 + j*64 + b0w) = f32x4{s0,s1,s2,s3};
    }
    gbar(slots, epoch, wg, tid, 3*t + 4);
  }

  // ---------------- finale ----------------
  if (wg == 0 && tid < 64){
    float s = 0.f;
    const float* yp = yout + 2048 + tid;   // parity of t=1023 is 1
    #pragma unroll
    for (int jj = 0; jj < 32; ++jj) s += yp[jj*64];
    out[(size_t)tid*TT + 1023] = fmaxf(s + bo2v, 0.f);
  }
  #pragma unroll
  for (int k = 0; k < 2; ++k){
    int g = wg*512 + k*256 + tid;
    if (g < 32768) out[65536 + g] = bf2f(h0hi[g]) + bf2f(h0lo[g]);
    else           out[65536 + g] = bf2f(h1hi[g-32768]) + bf2f(h1lo[g-32768]);
  }
}

extern "C" void kernel_launch(void* const* d_in, const int* in_sizes, int n_in,
                              void* d_out, int out_size, void* d_ws, size_t ws_size,
                              hipStream_t stream){
  const float* ctx   = (const float*)d_in[0];
  const float* Wih0  = (const float*)d_in[2];
  const float* Whh0  = (const float*)d_in[3];
  const float* bih0  = (const float*)d_in[4];
  const float* bhh0  = (const float*)d_in[5];
  const float* Wih1  = (const float*)d_in[6];
  const float* Whh1  = (const float*)d_in[7];
  const float* bih1  = (const float*)d_in[8];
  const float* bhh1  = (const float*)d_in[9];
  const float* Wo1   = (const float*)d_in[10];
  const float* bo1   = (const float*)d_in[11];
  const float* Wo2   = (const float*)d_in[12];
  const float* bo2   = (const float*)d_in[13];

  (void)in_sizes; (void)n_in; (void)out_size; (void)ws_size;

  (void)hipFuncSetAttribute((const void*)decoder_rnn,
                            hipFuncAttributeMaxDynamicSharedMemorySize,
                            (int)sizeof(Smem));

  decoder_rnn<<<NWG, NT, sizeof(Smem), stream>>>(
      ctx, Wih0, Whh0, bih0, bhh0, Wih1, Whh1, bih1, bhh1,
      Wo1, bo1, Wo2, bo2, (float*)d_out, (float*)d_ws);
}